// Round 18
// baseline (294.652 us; speedup 1.0000x reference)
//
#include <hip/hip_runtime.h>
#include <hip/hip_bf16.h>
#include <math.h>

#define NN 20000
#define NE 320000
#define DD 256
#define NH 8
#define KK 32
#define NR 5
#define NC 16
#define NB2 391   // ceil(NN*NR/256)

typedef unsigned short u16;
typedef unsigned int u32;
typedef __attribute__((ext_vector_type(8))) short bf16x8;
typedef __attribute__((ext_vector_type(4))) float f32x4;

__device__ __forceinline__ float bf2f(u16 v){ return __uint_as_float(((u32)v)<<16); }
__device__ __forceinline__ u16 f2bf(float f){
  u32 u = __float_as_uint(f);
  return (u16)((u + 0x7FFFu + ((u>>16)&1u)) >> 16);
}

// ---------------- pre1: nb_count + deg + perm=-1 init (independent block ranges) --------
__global__ void k_pre1(const int* __restrict__ ntype, const int* __restrict__ ei,
                       const int* __restrict__ etype, int* __restrict__ cnt,
                       int* __restrict__ off2, int* __restrict__ perm){
  int b = blockIdx.x;
  if(b < 79){
    int n = b*256 + threadIdx.x;
    int t = (n < NN) ? ntype[n] : -1;
    int lane = threadIdx.x & 63;
    #pragma unroll
    for(int tt=0; tt<3; tt++){
      unsigned long long mask = __ballot(t == tt);
      int leader = __ffsll((long long)mask) - 1;
      if(lane == leader) atomicAdd(&cnt[tt], __popcll(mask));
    }
  } else if(b < 1329){
    int e = (b-79)*256 + threadIdx.x;
    if(e < NE) atomicAdd(&off2[ei[NE + e]*NR + etype[e]], 1);
  } else {
    int i = (b-1329)*256 + threadIdx.x;
    if(i < 20096) perm[i] = -1;
  }
}

// ---------------- pre2: scan1 (block-local exclusive scan) + nb_off (extra block) --------
__global__ __launch_bounds__(256) void k_pre2(int* __restrict__ off2, int* __restrict__ bsum,
                                              const int* __restrict__ cnt, int* __restrict__ boff){
  if(blockIdx.x == NB2){
    if(threadIdx.x == 0){
      int a = (cnt[0]+31)&~31;
      int bb = (cnt[1]+31)&~31;
      boff[0]=0; boff[1]=a; boff[2]=a+bb;
    }
    return;
  }
  __shared__ int sh[256];
  int t = threadIdx.x;
  int i = blockIdx.x*256 + t;
  int v = (i < NN*NR) ? off2[i] : 0;
  sh[t] = v;
  __syncthreads();
  for(int off=1; off<256; off<<=1){
    int val = (t >= off) ? sh[t-off] : 0;
    __syncthreads();
    sh[t] += val;
    __syncthreads();
  }
  if(i < NN*NR) off2[i] = sh[t] - v;          // exclusive within block
  if(t == 255) bsum[blockIdx.x] = sh[255];    // block total
}
__global__ __launch_bounds__(512) void k_scan2(int* __restrict__ bsum, int* __restrict__ off2){
  __shared__ int sh[512];
  int t = threadIdx.x;
  int v = (t < NB2) ? bsum[t] : 0;
  sh[t] = v;
  __syncthreads();
  for(int off=1; off<512; off<<=1){
    int val = (t >= off) ? sh[t-off] : 0;
    __syncthreads();
    sh[t] += val;
    __syncthreads();
  }
  if(t < NB2) bsum[t] = sh[t] - v;            // exclusive block offsets
  if(t == 511) off2[NN*NR] = sh[511];         // grand total
}
// ---------------- pre3: scan3 + nb_scatter (+ inverse perm pos2) ----------------
__global__ void k_pre3(int* __restrict__ off2, const int* __restrict__ bsum,
                       const int* __restrict__ ntype, const int* __restrict__ boff,
                       int* __restrict__ bcur, int* __restrict__ perm,
                       int* __restrict__ pos2){
  int b = blockIdx.x;
  if(b < NB2){
    int i = b*256 + threadIdx.x;
    if(i < NN*NR) off2[i] += bsum[b];
  } else {
    int n = (b-NB2)*256 + threadIdx.x;
    int t = (n < NN) ? ntype[n] : -1;
    int lane = threadIdx.x & 63;
    #pragma unroll
    for(int tt=0; tt<3; tt++){
      unsigned long long mask = __ballot(t == tt);
      if(t == tt){
        int rank = __popcll(mask & ((1ull<<lane)-1ull));
        int leader = __ffsll((long long)mask) - 1;
        int base = 0;
        if(lane == leader) base = atomicAdd(&bcur[tt], __popcll(mask));
        base = __shfl(base, leader);
        int p = boff[tt] + base + rank;
        perm[p] = n;
        pos2[n] = p;               // inverse perm: aggrV stored in perm order
      }
    }
  }
}

// ---------------- work1: escatter + castx + castw + castsmall (independent ranges) ------
__global__ __launch_bounds__(256) void k_work1(
    const int* __restrict__ ei, const int* __restrict__ etype,
    int* __restrict__ off2, int* __restrict__ packed,
    const float* __restrict__ x, u16* __restrict__ xb,
    const float* __restrict__ Wk, const float* __restrict__ Wq,
    const float* __restrict__ Wv, const float* __restrict__ Wa,
    u16* __restrict__ Wtk, u16* __restrict__ Wtq,
    u16* __restrict__ Wtv, u16* __restrict__ Wta,
    const float* __restrict__ rmsg, const float* __restrict__ ratt,
    const float* __restrict__ prior, const float* __restrict__ Wo,
    u16* __restrict__ Mtm, u16* __restrict__ Atb, u16* __restrict__ Wot)
{
  __shared__ float tile[32][33];
  int b = blockIdx.x;
  if(b < 1250){
    int e = b*256 + threadIdx.x;
    if(e < NE){
      int pos = atomicAdd(&off2[ei[NE+e]*NR + etype[e]], 1);
      packed[pos] = ei[e];
    }
  } else if(b < 3750){
    int i = (b-1250)*256 + threadIdx.x;     // castx: 8 floats per thread
    float4 v0 = ((const float4*)x)[i*2+0];
    float4 v1 = ((const float4*)x)[i*2+1];
    uint4 o;
    o.x = (u32)f2bf(v0.x) | ((u32)f2bf(v0.y)<<16);
    o.y = (u32)f2bf(v0.z) | ((u32)f2bf(v0.w)<<16);
    o.z = (u32)f2bf(v1.x) | ((u32)f2bf(v1.y)<<16);
    o.w = (u32)f2bf(v1.z) | ((u32)f2bf(v1.w)<<16);
    ((uint4*)xb)[i] = o;
  } else if(b < 4518){
    int bp = b - 3750;                      // castw: 768 tiles = 8 x 8 x 12
    int bx = bp & 7, by = (bp>>3) & 7, z = bp >> 6;
    int tensor = z/3, t = z%3;
    const float* W = (tensor==0) ? Wk : (tensor==1) ? Wq : (tensor==2) ? Wv : Wa;
    u16* O = (tensor==0) ? Wtk : (tensor==1) ? Wtq : (tensor==2) ? Wtv : Wta;
    int i0 = bx*32, j0 = by*32;
    int rr = threadIdx.x>>5, cc = threadIdx.x&31;
    #pragma unroll
    for(int p=0;p<4;p++)
      tile[rr+p*8][cc] = W[t*65536 + (i0+rr+p*8)*256 + j0+cc];
    __syncthreads();
    #pragma unroll
    for(int p=0;p<4;p++)
      O[t*65536 + (j0+rr+p*8)*256 + i0+cc] = f2bf(tile[cc][rr+p*8]);
  } else {
    int bp = b - 4518;                      // castsmall: 336 blocks
    if(bp < 160){
      int idx = bp*256 + threadIdx.x;       // rel_msg transpose: [r,h,k,l] -> [r,h,l,k]
      int l = idx & 31, k = (idx >> 5) & 31, rh = idx >> 10;
      Mtm[(rh*32 + l)*32 + k] = f2bf(rmsg[idx]);
    } else if(bp < 320){
      int idx = (bp-160)*256 + threadIdx.x; // rel_att cast w/ prior/sqrtK folded
      int rh = idx >> 10;
      float scale = prior[rh] * 0.17677669529663687f;  // 1/sqrt(32)
      Atb[idx] = f2bf(ratt[idx] * scale);
    } else {
      int idx = (bp-320)*256 + threadIdx.x; // W_out transpose: [k,c] -> [c,k]
      int c = idx & 15, k = idx >> 4;
      Wot[c*DD + k] = f2bf(Wo[k*NC + c]);
    }
  }
}

// ---------------- FUSED typed K/Q/V projections + QA bilinear via MFMA ----------------
// Each wave owns ONE head (32-col stripe). QA phase is now BARRIER-FREE: Q-staging,
// Q-frag loads, QA C-layout staging and read-back all touch only the wave's own
// stripe (wave-internal LDS ordering suffices). QA global writes are per-wave 64B
// row segments (4x uint4) — still coalesced. R17 had 11 __syncthreads here; 0 now.
#define XSP 264   // padded row (u16): A-frag reads 2-way aliased only (free)
__global__ __launch_bounds__(256) void k_projqa(
    const u16* __restrict__ xb, const int* __restrict__ perm, const int* __restrict__ boff,
    const u16* __restrict__ Wtk, const u16* __restrict__ Wtq, const u16* __restrict__ Wtv,
    const float* __restrict__ bk, const float* __restrict__ bq, const float* __restrict__ bv,
    const u16* __restrict__ Atb,
    u16* __restrict__ KVn, u16* __restrict__ QA)
{
  __shared__ u16 smem[32*XSP];   // x-tile -> KV-stage -> per-wave Q/QA stripes
  __shared__ int gids[32];
  int tid = threadIdx.x;
  int ts = (blockIdx.x >> 1)*32;
  int cb = (blockIdx.x & 1)*128;          // column base for this block
  int t = (ts >= boff[2]) ? 2 : (ts >= boff[1]) ? 1 : 0;   // boff 32-aligned
  if(tid < 32) gids[tid] = perm[ts + tid];
  __syncthreads();
  #pragma unroll
  for(int it=0; it<4; it++){
    int q = tid + it*256;
    int row = q >> 5, c = q & 31;
    int g = gids[row];
    uint4 v = make_uint4(0,0,0,0);
    if(g >= 0) v = ((const uint4*)(xb + (size_t)g*DD))[c];
    ((uint4*)(smem + row*XSP))[c] = v;
  }
  __syncthreads();
  int lane = tid & 63;
  int w = tid >> 6;
  int quad = lane >> 4;
  int l16 = lane & 15;
  f32x4 accK[2][2], accQ[2][2], accV[2][2];   // [mt][nt]
  #pragma unroll
  for(int mt=0;mt<2;mt++)
    #pragma unroll
    for(int nt=0;nt<2;nt++){
      accK[mt][nt]=(f32x4)(0.f); accQ[mt][nt]=(f32x4)(0.f); accV[mt][nt]=(f32x4)(0.f);
    }
  const u16* wkp = Wtk + (size_t)t*65536;
  const u16* wqp = Wtq + (size_t)t*65536;
  const u16* wvp = Wtv + (size_t)t*65536;
  #pragma unroll
  for(int kk=0; kk<8; kk++){
    int kb = kk*32 + quad*8;
    bf16x8 a0 = *(const bf16x8*)(smem + l16*XSP + kb);
    bf16x8 a1 = *(const bf16x8*)(smem + (16+l16)*XSP + kb);
    #pragma unroll
    for(int nt=0; nt<2; nt++){
      int n = cb + w*32 + nt*16 + l16;
      bf16x8 bK = *(const bf16x8*)(wkp + (size_t)n*DD + kb);
      bf16x8 bQ = *(const bf16x8*)(wqp + (size_t)n*DD + kb);
      bf16x8 bV = *(const bf16x8*)(wvp + (size_t)n*DD + kb);
      accK[0][nt] = __builtin_amdgcn_mfma_f32_16x16x32_bf16(a0, bK, accK[0][nt], 0,0,0);
      accK[1][nt] = __builtin_amdgcn_mfma_f32_16x16x32_bf16(a1, bK, accK[1][nt], 0,0,0);
      accQ[0][nt] = __builtin_amdgcn_mfma_f32_16x16x32_bf16(a0, bQ, accQ[0][nt], 0,0,0);
      accQ[1][nt] = __builtin_amdgcn_mfma_f32_16x16x32_bf16(a1, bQ, accQ[1][nt], 0,0,0);
      accV[0][nt] = __builtin_amdgcn_mfma_f32_16x16x32_bf16(a0, bV, accV[0][nt], 0,0,0);
      accV[1][nt] = __builtin_amdgcn_mfma_f32_16x16x32_bf16(a1, bV, accV[1][nt], 0,0,0);
    }
  }
  __syncthreads();                 // x-tile dead; reuse smem as KV stage
  #pragma unroll
  for(int nt=0; nt<2; nt++){
    int lc = w*32 + nt*16 + l16;   // local col 0..127
    int colg = cb + lc;
    int kvo = ((lc >> 2)*8 + (lc & 3));
    float bkv = bk[t*DD+colg], bvv = bv[t*DD+colg];
    #pragma unroll
    for(int mt=0; mt<2; mt++){
      #pragma unroll
      for(int reg=0; reg<4; reg++){
        int row = mt*16 + quad*4 + reg;
        smem[row*XSP + kvo]     = f2bf(accK[mt][nt][reg] + bkv);
        smem[row*XSP + kvo + 4] = f2bf(accV[mt][nt][reg] + bvv);
      }
    }
  }
  __syncthreads();
  #pragma unroll
  for(int it=0; it<4; it++){       // 1024 uint4: 32 rows x 32 (cross-wave reads)
    int q = tid + it*256;
    int row = q >> 5, c = q & 31;
    int g = gids[row];
    if(g >= 0)
      *(uint4*)(KVn + (size_t)g*512 + (cb>>2)*8 + c*8) = ((uint4*)(smem + row*XSP))[c];
  }
  __syncthreads();                 // last cross-wave use of smem; stripes private below

  // ---- Q stage (per-wave stripe; wave-internal LDS ordering only) ----
  #pragma unroll
  for(int nt=0; nt<2; nt++){
    int lc = w*32 + nt*16 + l16;
    float bqv = bq[t*DD + cb + lc];
    #pragma unroll
    for(int mt=0; mt<2; mt++){
      #pragma unroll
      for(int reg=0; reg<4; reg++){
        int row = mt*16 + quad*4 + reg;
        smem[row*XSP + lc] = f2bf(accQ[mt][nt][reg] + bqv);
      }
    }
  }
  int h = (cb >> 5) + w;
  bf16x8 qf0 = *(const bf16x8*)(smem + l16*XSP + w*32 + quad*8);
  bf16x8 qf1 = *(const bf16x8*)(smem + (16+l16)*XSP + w*32 + quad*8);

  // ---- QA stage: 5 relations, zero barriers ----
  for(int r=0; r<NR; r++){
    f32x4 acc[2][2];   // [mt][nt]
    #pragma unroll
    for(int mt=0;mt<2;mt++)
      #pragma unroll
      for(int nt=0;nt<2;nt++) acc[mt][nt]=(f32x4)(0.f);
    const u16* ap = Atb + (size_t)(r*NH + h)*1024;
    bf16x8 b0 = *(const bf16x8*)(ap + l16*32 + quad*8);
    bf16x8 b1 = *(const bf16x8*)(ap + (16+l16)*32 + quad*8);
    acc[0][0] = __builtin_amdgcn_mfma_f32_16x16x32_bf16(qf0, b0, acc[0][0], 0,0,0);
    acc[0][1] = __builtin_amdgcn_mfma_f32_16x16x32_bf16(qf0, b1, acc[0][1], 0,0,0);
    acc[1][0] = __builtin_amdgcn_mfma_f32_16x16x32_bf16(qf1, b0, acc[1][0], 0,0,0);
    acc[1][1] = __builtin_amdgcn_mfma_f32_16x16x32_bf16(qf1, b1, acc[1][1], 0,0,0);
    // C-layout -> own stripe (in-wave ordering; r-1's reads already retired in-order)
    #pragma unroll
    for(int mt=0; mt<2; mt++)
      #pragma unroll
      for(int nt=0; nt<2; nt++)
        #pragma unroll
        for(int reg=0; reg<4; reg++){
          int row = mt*16 + quad*4 + reg;
          smem[row*XSP + w*32 + nt*16 + l16] = f2bf(acc[mt][nt][reg]);
        }
    // per-wave write-out: 32 rows x 4 uint4 (64B/row segment), 2 iters of 64 lanes
    #pragma unroll
    for(int it=0; it<2; it++){
      int idx = it*64 + lane;
      int row = idx >> 2, c = idx & 3;
      int g = gids[row];
      if(g >= 0)
        *(uint4*)(QA + ((size_t)g*NR + r)*DD + cb + w*32 + c*8)
          = ((uint4*)(smem + row*XSP + w*32))[c];
    }
  }
}

// ---------------- fused per-node softmax + aggregation: r-sorted, batched gathers ----------
// (R12 structure — latency/fabric floor for random 1KB gathers.)
#define VSP 264
__global__ __launch_bounds__(256) void k_edge(
    const u16* __restrict__ KVn, const u16* __restrict__ QA,
    const int* __restrict__ off2, const int* __restrict__ packed,
    const int* __restrict__ pos2, u16* __restrict__ aggrV)
{
  int lane = threadIdx.x & 63;
  int n = blockIdx.x*4 + (threadIdx.x >> 6);
  if(n >= NN) return;
  int off = lane*4;                  // = h*32 + j*4 with h=lane>>3
  float4 qa[NR];
  {
    const u16* qp = QA + (size_t)n*NR*DD + off;
    #pragma unroll
    for(int r=0;r<NR;r++){
      ushort4 q = *(const ushort4*)(qp + r*DD);
      qa[r] = make_float4(bf2f(q.x),bf2f(q.y),bf2f(q.z),bf2f(q.w));
    }
  }
  int eb[NR+1];
  eb[0] = (n==0) ? 0 : off2[n*NR - 1];
  #pragma unroll
  for(int i=1;i<=NR;i++) eb[i] = off2[n*NR + i - 1];
  float4 acc[NR];
  float s = 0.f;
  int lo8 = lane*8;

  #define EDGE_DOT(kv, q, dd) \
    { float k0=__uint_as_float((kv).x<<16), k1=__uint_as_float((kv).x&0xffff0000u); \
      float k2=__uint_as_float((kv).y<<16), k3=__uint_as_float((kv).y&0xffff0000u); \
      dd = k0*(q).x + k1*(q).y + k2*(q).z + k3*(q).w; }
  #define EDGE_ACC(kv, p, a) \
    { float v0=__uint_as_float((kv).z<<16), v1=__uint_as_float((kv).z&0xffff0000u); \
      float v2=__uint_as_float((kv).w<<16), v3=__uint_as_float((kv).w&0xffff0000u); \
      (a).x += (p)*v0; (a).y += (p)*v1; (a).z += (p)*v2; (a).w += (p)*v3; }
  #define RED3(d) { d += __shfl_xor(d,1); d += __shfl_xor(d,2); d += __shfl_xor(d,4); }

  #pragma unroll
  for(int r=0;r<NR;r++){
    float4 q = qa[r];
    float4 a = make_float4(0.f,0.f,0.f,0.f);
    int e = eb[r], end = eb[r+1];
    for(; e+4 <= end; e += 4){
      int s0 = packed[e], s1 = packed[e+1], s2 = packed[e+2], s3 = packed[e+3];
      uint4 kv0 = *(const uint4*)(KVn + (size_t)s0*512 + lo8);
      uint4 kv1 = *(const uint4*)(KVn + (size_t)s1*512 + lo8);
      uint4 kv2 = *(const uint4*)(KVn + (size_t)s2*512 + lo8);
      uint4 kv3 = *(const uint4*)(KVn + (size_t)s3*512 + lo8);
      float d0,d1,d2,d3;
      EDGE_DOT(kv0,q,d0); EDGE_DOT(kv1,q,d1); EDGE_DOT(kv2,q,d2); EDGE_DOT(kv3,q,d3);
      RED3(d0); RED3(d1); RED3(d2); RED3(d3);
      float p0=__expf(d0), p1=__expf(d1), p2=__expf(d2), p3=__expf(d3);
      s += p0 + p1 + p2 + p3;
      EDGE_ACC(kv0,p0,a); EDGE_ACC(kv1,p1,a); EDGE_ACC(kv2,p2,a); EDGE_ACC(kv3,p3,a);
    }
    if(e+2 <= end){
      int s0 = packed[e], s1 = packed[e+1];
      uint4 kv0 = *(const uint4*)(KVn + (size_t)s0*512 + lo8);
      uint4 kv1 = *(const uint4*)(KVn + (size_t)s1*512 + lo8);
      float d0,d1;
      EDGE_DOT(kv0,q,d0); EDGE_DOT(kv1,q,d1);
      RED3(d0); RED3(d1);
      float p0=__expf(d0), p1=__expf(d1);
      s += p0 + p1;
      EDGE_ACC(kv0,p0,a); EDGE_ACC(kv1,p1,a);
      e += 2;
    }
    if(e < end){
      int s0 = packed[e];
      uint4 kv0 = *(const uint4*)(KVn + (size_t)s0*512 + lo8);
      float d0;
      EDGE_DOT(kv0,q,d0);
      RED3(d0);
      float p0=__expf(d0);
      s += p0;
      EDGE_ACC(kv0,p0,a);
    }
    acc[r] = a;
  }
  #undef EDGE_DOT
  #undef EDGE_ACC
  #undef RED3
  float inv = (s > 0.f) ? (1.f/s) : 0.f;
  int p = pos2[n];                   // perm-order row for contiguous k_mo reads
  u16* op = aggrV + (size_t)p*NR*DD + off;
  #pragma unroll
  for(int r=0;r<NR;r++){
    ushort4 o;
    o.x=f2bf(acc[r].x*inv); o.y=f2bf(acc[r].y*inv);
    o.z=f2bf(acc[r].z*inv); o.w=f2bf(acc[r].w*inv);
    *(ushort4*)(op + r*DD) = o;
  }
}

// ---------------- FUSED k_msg + k_out (aggrV perm-ordered: contiguous reads) ----------
__global__ __launch_bounds__(256) void k_mo(
    const u16* __restrict__ aggrV, const u16* __restrict__ Mtm,
    const float* __restrict__ x,
    const int* __restrict__ perm, const int* __restrict__ boff,
    const u16* __restrict__ Wta, const float* __restrict__ ba,
    const u16* __restrict__ Wot, const float* __restrict__ bo,
    float* __restrict__ out)
{
  __shared__ u16 Vs[32*VSP];
  __shared__ u16 hs[32*VSP];
  __shared__ u16 h2s[32*VSP];
  __shared__ int gids[32];
  int tid = threadIdx.x;
  int ts = blockIdx.x*32;
  int t = (ts >= boff[2]) ? 2 : (ts >= boff[1]) ? 1 : 0;
  if(tid < 32) gids[tid] = perm[ts + tid];
  __syncthreads();
  int lane = tid & 63, w = tid >> 6, quad = lane >> 4, l16 = lane & 15;

  // ---- stage 1: rel_msg MFMA over r (pad rows hold poison; discarded by g>=0 guards) ----
  f32x4 macc[2][2][2];
  #pragma unroll
  for(int hh=0;hh<2;hh++)
    #pragma unroll
    for(int mt=0;mt<2;mt++)
      #pragma unroll
      for(int nt=0;nt<2;nt++) macc[hh][mt][nt]=(f32x4)(0.f);
  for(int r=0;r<NR;r++){
    __syncthreads();
    #pragma unroll
    for(int it=0; it<4; it++){
      int q = tid + it*256;
      int row = q >> 5, c = q & 31;
      ((uint4*)(Vs + row*VSP))[c] =
        ((const uint4*)(aggrV + ((size_t)(ts+row)*NR + r)*DD))[c];
    }
    __syncthreads();
    #pragma unroll
    for(int hh=0; hh<2; hh++){
      int h = w*2 + hh;
      bf16x8 a0 = *(const bf16x8*)(Vs + l16*VSP + h*32 + quad*8);
      bf16x8 a1 = *(const bf16x8*)(Vs + (16+l16)*VSP + h*32 + quad*8);
      const u16* mp = Mtm + ((size_t)(r*NH + h)*32)*32;
      bf16x8 b0 = *(const bf16x8*)(mp + l16*32 + quad*8);
      bf16x8 b1 = *(const bf16x8*)(mp + (16+l16)*32 + quad*8);
      macc[hh][0][0] = __builtin_amdgcn_mfma_f32_16x16x32_bf16(a0, b0, macc[hh][0][0], 0,0,0);
      macc[hh][0][1] = __builtin_amdgcn_mfma_f32_16x16x32_bf16(a0, b1, macc[hh][0][1], 0,0,0);
      macc[hh][1][0] = __builtin_amdgcn_mfma_f32_16x16x32_bf16(a1, b0, macc[hh][1][0], 0,0,0);
      macc[hh][1][1] = __builtin_amdgcn_mfma_f32_16x16x32_bf16(a1, b1, macc[hh][1][1], 0,0,0);
    }
  }
  // ELU -> hs (bf16, in LDS)
  #pragma unroll
  for(int hh=0; hh<2; hh++){
    int h = w*2 + hh;
    #pragma unroll
    for(int mt=0; mt<2; mt++){
      #pragma unroll
      for(int nt=0; nt<2; nt++){
        #pragma unroll
        for(int reg=0; reg<4; reg++){
          int row = mt*16 + quad*4 + reg;
          float v = macc[hh][mt][nt][reg];
          v = (v > 0.f) ? v : expm1f(v);
          hs[row*VSP + h*32 + nt*16 + l16] = f2bf(v);
        }
      }
    }
  }
  __syncthreads();

  // ---- stage 2: Wa MFMA + residual + classifier + log_softmax ----
  f32x4 acc[2][4];
  #pragma unroll
  for(int mt=0;mt<2;mt++)
    #pragma unroll
    for(int nt=0;nt<4;nt++) acc[mt][nt]=(f32x4)(0.f);
  const u16* wap = Wta + (size_t)t*65536;
  #pragma unroll
  for(int kk=0; kk<8; kk++){
    int kb = kk*32 + quad*8;
    bf16x8 a0 = *(const bf16x8*)(hs + l16*VSP + kb);
    bf16x8 a1 = *(const bf16x8*)(hs + (16+l16)*VSP + kb);
    #pragma unroll
    for(int nt=0; nt<4; nt++){
      int n = w*64 + nt*16 + l16;
      bf16x8 b = *(const bf16x8*)(wap + (size_t)n*DD + kb);
      acc[0][nt] = __builtin_amdgcn_mfma_f32_16x16x32_bf16(a0, b, acc[0][nt], 0,0,0);
      acc[1][nt] = __builtin_amdgcn_mfma_f32_16x16x32_bf16(a1, b, acc[1][nt], 0,0,0);
    }
  }
  #pragma unroll
  for(int nt=0; nt<4; nt++){
    int colg = w*64 + nt*16 + l16;
    float bav = ba[t*DD + colg];
    #pragma unroll
    for(int mt=0; mt<2; mt++){
      #pragma unroll
      for(int reg=0; reg<4; reg++){
        int row = mt*16 + quad*4 + reg;
        int g = gids[row];
        float xr = (g>=0) ? x[(size_t)g*DD + colg] : 0.f;
        h2s[row*VSP + colg] = f2bf(acc[mt][nt][reg] + bav + xr);
      }
    }
  }
  __syncthreads();
  if(w < 2){
    f32x4 cacc = (f32x4)(0.f);
    #pragma unroll
    for(int kk=0; kk<8; kk++){
      int kb = kk*32 + quad*8;
      bf16x8 a = *(const bf16x8*)(h2s + (w*16 + l16)*VSP + kb);
      bf16x8 b = *(const bf16x8*)(Wot + (size_t)l16*DD + kb);
      cacc = __builtin_amdgcn_mfma_f32_16x16x32_bf16(a, b, cacc, 0,0,0);
    }
    float bov = bo[l16];
    #pragma unroll
    for(int reg=0; reg<4; reg++){
      int row = w*16 + quad*4 + reg;
      int g = gids[row];
      float v = cacc[reg] + bov;     // col = l16 = class
      float m = v;
      m = fmaxf(m, __shfl_xor(m,1)); m = fmaxf(m, __shfl_xor(m,2));
      m = fmaxf(m, __shfl_xor(m,4)); m = fmaxf(m, __shfl_xor(m,8));
      float p = __expf(v - m);
      p += __shfl_xor(p,1); p += __shfl_xor(p,2);
      p += __shfl_xor(p,4); p += __shfl_xor(p,8);
      float lse = m + __logf(p);
      if(g >= 0) out[(size_t)g*NC + l16] = v - lse;
    }
  }
}

extern "C" void kernel_launch(void* const* d_in, const int* in_sizes, int n_in,
                              void* d_out, int out_size, void* d_ws, size_t ws_size,
                              hipStream_t stream)
{
  const float* x     = (const float*)d_in[0];
  const int*   ei    = (const int*)d_in[1];
  const int*   ntype = (const int*)d_in[2];
  const int*   etype = (const int*)d_in[3];
  const float* Wk    = (const float*)d_in[4];
  const float* bk    = (const float*)d_in[5];
  const float* Wq    = (const float*)d_in[6];
  const float* bq    = (const float*)d_in[7];
  const float* Wv    = (const float*)d_in[8];
  const float* bv    = (const float*)d_in[9];
  const float* Wa    = (const float*)d_in[10];
  const float* ba    = (const float*)d_in[11];
  const float* prior = (const float*)d_in[12];
  const float* ratt  = (const float*)d_in[13];
  const float* rmsg  = (const float*)d_in[14];
  const float* Wo    = (const float*)d_in[15];
  const float* bo    = (const float*)d_in[16];
  float* out = (float*)d_out;

  char* ws = (char*)d_ws;
  int* iw      = (int*)ws;
  int* cnt     = iw + 0;
  int* bcur    = iw + 4;
  int* boff    = iw + 8;
  int* off2    = iw + 16;                 // NN*NR+1 = 100001 ints
  int* perm    = iw + 100032;             // 20096 ints
  int* packed  = iw + 120128;             // NE ints (ends 440128)
  int* bsum    = iw + 440128;             // 512 ints (ends 440640)
  int* pos2    = iw + 440640;             // NN ints (ends 460640)

  size_t fb = 1842688;                    // 460640*4 = 1842560, 256-aligned up
  u16*   KVn   = (u16*)(ws + fb);   fb += 2ull*NN*512;         // 20.48 MB (K,V interleaved)
  u16*   QA    = (u16*)(ws + fb);   fb += 2ull*NN*NR*DD;       // 51.2 MB
  u16*   aggrV = (u16*)(ws + fb);   fb += 2ull*20096*NR*DD;    // 51.45 MB (perm-order, padded)
  u16*   Wtk   = (u16*)(ws + fb);   fb += 2ull*3*65536;
  u16*   Wtq   = (u16*)(ws + fb);   fb += 2ull*3*65536;
  u16*   Wtv   = (u16*)(ws + fb);   fb += 2ull*3*65536;
  u16*   Wta   = (u16*)(ws + fb);   fb += 2ull*3*65536;
  u16*   Wot   = (u16*)(ws + fb);   fb += 2ull*NC*DD;
  u16*   Mtm   = (u16*)(ws + fb);   fb += 2ull*NR*NH*KK*KK;
  u16*   Atb   = (u16*)(ws + fb);   fb += 2ull*NR*NH*KK*KK;
  // total ~127 MB (validated high-water mark: 165.6 MB)
  u16* xb = aggrV;                        // NN*DD bf16 alias; dead before k_edge writes

  hipMemsetAsync(iw, 0, (size_t)(16 + NN*NR + 1)*sizeof(int), stream); // cnt,bcur,boff,off2

  k_pre1   <<<1408, 256, 0, stream>>>(ntype, ei, etype, cnt, off2, perm);
  k_pre2   <<<NB2+1, 256, 0, stream>>>(off2, bsum, cnt, boff);
  k_scan2  <<<1, 512, 0, stream>>>(bsum, off2);
  k_pre3   <<<NB2+79, 256, 0, stream>>>(off2, bsum, ntype, boff, bcur, perm, pos2);
  k_work1  <<<4854, 256, 0, stream>>>(ei, etype, off2, packed, x, xb,
                                      Wk, Wq, Wv, Wa, Wtk, Wtq, Wtv, Wta,
                                      rmsg, ratt, prior, Wo, Mtm, Atb, Wot);
  k_projqa <<<1256, 256, 0, stream>>>(xb, perm, boff, Wtk, Wtq, Wtv, bk, bq, bv,
                                      Atb, KVn, QA);
  k_edge   <<<5000, 256, 0, stream>>>(KVn, QA, off2, packed, pos2, aggrV);
  k_mo     <<<628, 256, 0, stream>>>(aggrV, Mtm, x, perm, boff, Wta, ba, Wot, bo, out);
}

// Round 19
// 293.777 us; speedup vs baseline: 1.0030x; 1.0030x over previous
//
#include <hip/hip_runtime.h>
#include <hip/hip_bf16.h>
#include <math.h>

#define NN 20000
#define NE 320000
#define DD 256
#define NH 8
#define KK 32
#define NR 5
#define NC 16
#define NB2 391   // ceil(NN*NR/256)

typedef unsigned short u16;
typedef unsigned int u32;
typedef __attribute__((ext_vector_type(8))) short bf16x8;
typedef __attribute__((ext_vector_type(4))) float f32x4;

__device__ __forceinline__ float bf2f(u16 v){ return __uint_as_float(((u32)v)<<16); }
__device__ __forceinline__ u16 f2bf(float f){
  u32 u = __float_as_uint(f);
  return (u16)((u + 0x7FFFu + ((u>>16)&1u)) >> 16);
}

// ---------------- pre1: nb_count + deg + perm=-1 init (independent block ranges) --------
__global__ void k_pre1(const int* __restrict__ ntype, const int* __restrict__ ei,
                       const int* __restrict__ etype, int* __restrict__ cnt,
                       int* __restrict__ off2, int* __restrict__ perm){
  int b = blockIdx.x;
  if(b < 79){
    int n = b*256 + threadIdx.x;
    int t = (n < NN) ? ntype[n] : -1;
    int lane = threadIdx.x & 63;
    #pragma unroll
    for(int tt=0; tt<3; tt++){
      unsigned long long mask = __ballot(t == tt);
      int leader = __ffsll((long long)mask) - 1;
      if(lane == leader) atomicAdd(&cnt[tt], __popcll(mask));
    }
  } else if(b < 1329){
    int e = (b-79)*256 + threadIdx.x;
    if(e < NE) atomicAdd(&off2[ei[NE + e]*NR + etype[e]], 1);
  } else {
    int i = (b-1329)*256 + threadIdx.x;
    if(i < 20096) perm[i] = -1;
  }
}

// ---------------- pre2: scan1 (block-local exclusive scan) + nb_off (extra block) --------
__global__ __launch_bounds__(256) void k_pre2(int* __restrict__ off2, int* __restrict__ bsum,
                                              const int* __restrict__ cnt, int* __restrict__ boff){
  if(blockIdx.x == NB2){
    if(threadIdx.x == 0){
      int a = (cnt[0]+31)&~31;
      int bb = (cnt[1]+31)&~31;
      boff[0]=0; boff[1]=a; boff[2]=a+bb;
    }
    return;
  }
  __shared__ int sh[256];
  int t = threadIdx.x;
  int i = blockIdx.x*256 + t;
  int v = (i < NN*NR) ? off2[i] : 0;
  sh[t] = v;
  __syncthreads();
  for(int off=1; off<256; off<<=1){
    int val = (t >= off) ? sh[t-off] : 0;
    __syncthreads();
    sh[t] += val;
    __syncthreads();
  }
  if(i < NN*NR) off2[i] = sh[t] - v;          // exclusive within block
  if(t == 255) bsum[blockIdx.x] = sh[255];    // block total
}
__global__ __launch_bounds__(512) void k_scan2(int* __restrict__ bsum, int* __restrict__ off2){
  __shared__ int sh[512];
  int t = threadIdx.x;
  int v = (t < NB2) ? bsum[t] : 0;
  sh[t] = v;
  __syncthreads();
  for(int off=1; off<512; off<<=1){
    int val = (t >= off) ? sh[t-off] : 0;
    __syncthreads();
    sh[t] += val;
    __syncthreads();
  }
  if(t < NB2) bsum[t] = sh[t] - v;            // exclusive block offsets
  if(t == 511) off2[NN*NR] = sh[511];         // grand total
}
// ---------------- pre3: scan3 + nb_scatter (+ inverse perm pos2) ----------------
__global__ void k_pre3(int* __restrict__ off2, const int* __restrict__ bsum,
                       const int* __restrict__ ntype, const int* __restrict__ boff,
                       int* __restrict__ bcur, int* __restrict__ perm,
                       int* __restrict__ pos2){
  int b = blockIdx.x;
  if(b < NB2){
    int i = b*256 + threadIdx.x;
    if(i < NN*NR) off2[i] += bsum[b];
  } else {
    int n = (b-NB2)*256 + threadIdx.x;
    int t = (n < NN) ? ntype[n] : -1;
    int lane = threadIdx.x & 63;
    #pragma unroll
    for(int tt=0; tt<3; tt++){
      unsigned long long mask = __ballot(t == tt);
      if(t == tt){
        int rank = __popcll(mask & ((1ull<<lane)-1ull));
        int leader = __ffsll((long long)mask) - 1;
        int base = 0;
        if(lane == leader) base = atomicAdd(&bcur[tt], __popcll(mask));
        base = __shfl(base, leader);
        int p = boff[tt] + base + rank;
        perm[p] = n;
        pos2[n] = p;               // inverse perm: aggrV stored in perm order
      }
    }
  }
}

// ---------------- work1: escatter + castx + castw + castsmall (independent ranges) ------
__global__ __launch_bounds__(256) void k_work1(
    const int* __restrict__ ei, const int* __restrict__ etype,
    int* __restrict__ off2, int* __restrict__ packed,
    const float* __restrict__ x, u16* __restrict__ xb,
    const float* __restrict__ Wk, const float* __restrict__ Wq,
    const float* __restrict__ Wv, const float* __restrict__ Wa,
    u16* __restrict__ Wtk, u16* __restrict__ Wtq,
    u16* __restrict__ Wtv, u16* __restrict__ Wta,
    const float* __restrict__ rmsg, const float* __restrict__ ratt,
    const float* __restrict__ prior, const float* __restrict__ Wo,
    u16* __restrict__ Mtm, u16* __restrict__ Atb, u16* __restrict__ Wot)
{
  __shared__ float tile[32][33];
  int b = blockIdx.x;
  if(b < 1250){
    int e = b*256 + threadIdx.x;
    if(e < NE){
      int pos = atomicAdd(&off2[ei[NE+e]*NR + etype[e]], 1);
      packed[pos] = ei[e];
    }
  } else if(b < 3750){
    int i = (b-1250)*256 + threadIdx.x;     // castx: 8 floats per thread
    float4 v0 = ((const float4*)x)[i*2+0];
    float4 v1 = ((const float4*)x)[i*2+1];
    uint4 o;
    o.x = (u32)f2bf(v0.x) | ((u32)f2bf(v0.y)<<16);
    o.y = (u32)f2bf(v0.z) | ((u32)f2bf(v0.w)<<16);
    o.z = (u32)f2bf(v1.x) | ((u32)f2bf(v1.y)<<16);
    o.w = (u32)f2bf(v1.z) | ((u32)f2bf(v1.w)<<16);
    ((uint4*)xb)[i] = o;
  } else if(b < 4518){
    int bp = b - 3750;                      // castw: 768 tiles = 8 x 8 x 12
    int bx = bp & 7, by = (bp>>3) & 7, z = bp >> 6;
    int tensor = z/3, t = z%3;
    const float* W = (tensor==0) ? Wk : (tensor==1) ? Wq : (tensor==2) ? Wv : Wa;
    u16* O = (tensor==0) ? Wtk : (tensor==1) ? Wtq : (tensor==2) ? Wtv : Wta;
    int i0 = bx*32, j0 = by*32;
    int rr = threadIdx.x>>5, cc = threadIdx.x&31;
    #pragma unroll
    for(int p=0;p<4;p++)
      tile[rr+p*8][cc] = W[t*65536 + (i0+rr+p*8)*256 + j0+cc];
    __syncthreads();
    #pragma unroll
    for(int p=0;p<4;p++)
      O[t*65536 + (j0+rr+p*8)*256 + i0+cc] = f2bf(tile[cc][rr+p*8]);
  } else {
    int bp = b - 4518;                      // castsmall: 336 blocks
    if(bp < 160){
      int idx = bp*256 + threadIdx.x;       // rel_msg transpose: [r,h,k,l] -> [r,h,l,k]
      int l = idx & 31, k = (idx >> 5) & 31, rh = idx >> 10;
      Mtm[(rh*32 + l)*32 + k] = f2bf(rmsg[idx]);
    } else if(bp < 320){
      int idx = (bp-160)*256 + threadIdx.x; // rel_att cast w/ prior/sqrtK folded
      int rh = idx >> 10;
      float scale = prior[rh] * 0.17677669529663687f;  // 1/sqrt(32)
      Atb[idx] = f2bf(ratt[idx] * scale);
    } else {
      int idx = (bp-320)*256 + threadIdx.x; // W_out transpose: [k,c] -> [c,k]
      int c = idx & 15, k = idx >> 4;
      Wot[c*DD + k] = f2bf(Wo[k*NC + c]);
    }
  }
}

// ---------------- FUSED typed K/Q/V projections + QA bilinear via MFMA ----------------
// QA tail reverted to R17 barriered form (57.6us measured): R18's barrier-free
// per-wave write-out regressed to 67us via LDS bank conflicts + 64B global segments.
#define XSP 264   // padded row (u16): A-frag reads 2-way aliased only (free)
__global__ __launch_bounds__(256) void k_projqa(
    const u16* __restrict__ xb, const int* __restrict__ perm, const int* __restrict__ boff,
    const u16* __restrict__ Wtk, const u16* __restrict__ Wtq, const u16* __restrict__ Wtv,
    const float* __restrict__ bk, const float* __restrict__ bq, const float* __restrict__ bv,
    const u16* __restrict__ Atb,
    u16* __restrict__ KVn, u16* __restrict__ QA)
{
  __shared__ u16 smem[32*XSP];   // x-tile -> KV-stage -> Q-stage -> QA-stage (reused)
  __shared__ int gids[32];
  int tid = threadIdx.x;
  int ts = (blockIdx.x >> 1)*32;
  int cb = (blockIdx.x & 1)*128;          // column base for this block
  int t = (ts >= boff[2]) ? 2 : (ts >= boff[1]) ? 1 : 0;   // boff 32-aligned
  if(tid < 32) gids[tid] = perm[ts + tid];
  __syncthreads();
  #pragma unroll
  for(int it=0; it<4; it++){
    int q = tid + it*256;
    int row = q >> 5, c = q & 31;
    int g = gids[row];
    uint4 v = make_uint4(0,0,0,0);
    if(g >= 0) v = ((const uint4*)(xb + (size_t)g*DD))[c];
    ((uint4*)(smem + row*XSP))[c] = v;
  }
  __syncthreads();
  int lane = tid & 63;
  int w = tid >> 6;
  int quad = lane >> 4;
  int l16 = lane & 15;
  f32x4 accK[2][2], accQ[2][2], accV[2][2];   // [mt][nt]
  #pragma unroll
  for(int mt=0;mt<2;mt++)
    #pragma unroll
    for(int nt=0;nt<2;nt++){
      accK[mt][nt]=(f32x4)(0.f); accQ[mt][nt]=(f32x4)(0.f); accV[mt][nt]=(f32x4)(0.f);
    }
  const u16* wkp = Wtk + (size_t)t*65536;
  const u16* wqp = Wtq + (size_t)t*65536;
  const u16* wvp = Wtv + (size_t)t*65536;
  #pragma unroll
  for(int kk=0; kk<8; kk++){
    int kb = kk*32 + quad*8;
    bf16x8 a0 = *(const bf16x8*)(smem + l16*XSP + kb);
    bf16x8 a1 = *(const bf16x8*)(smem + (16+l16)*XSP + kb);
    #pragma unroll
    for(int nt=0; nt<2; nt++){
      int n = cb + w*32 + nt*16 + l16;
      bf16x8 bK = *(const bf16x8*)(wkp + (size_t)n*DD + kb);
      bf16x8 bQ = *(const bf16x8*)(wqp + (size_t)n*DD + kb);
      bf16x8 bV = *(const bf16x8*)(wvp + (size_t)n*DD + kb);
      accK[0][nt] = __builtin_amdgcn_mfma_f32_16x16x32_bf16(a0, bK, accK[0][nt], 0,0,0);
      accK[1][nt] = __builtin_amdgcn_mfma_f32_16x16x32_bf16(a1, bK, accK[1][nt], 0,0,0);
      accQ[0][nt] = __builtin_amdgcn_mfma_f32_16x16x32_bf16(a0, bQ, accQ[0][nt], 0,0,0);
      accQ[1][nt] = __builtin_amdgcn_mfma_f32_16x16x32_bf16(a1, bQ, accQ[1][nt], 0,0,0);
      accV[0][nt] = __builtin_amdgcn_mfma_f32_16x16x32_bf16(a0, bV, accV[0][nt], 0,0,0);
      accV[1][nt] = __builtin_amdgcn_mfma_f32_16x16x32_bf16(a1, bV, accV[1][nt], 0,0,0);
    }
  }
  __syncthreads();                 // x-tile dead; reuse smem as KV stage
  #pragma unroll
  for(int nt=0; nt<2; nt++){
    int lc = w*32 + nt*16 + l16;   // local col 0..127
    int colg = cb + lc;
    int kvo = ((lc >> 2)*8 + (lc & 3));
    float bkv = bk[t*DD+colg], bvv = bv[t*DD+colg];
    #pragma unroll
    for(int mt=0; mt<2; mt++){
      #pragma unroll
      for(int reg=0; reg<4; reg++){
        int row = mt*16 + quad*4 + reg;
        smem[row*XSP + kvo]     = f2bf(accK[mt][nt][reg] + bkv);
        smem[row*XSP + kvo + 4] = f2bf(accV[mt][nt][reg] + bvv);
      }
    }
  }
  __syncthreads();
  #pragma unroll
  for(int it=0; it<4; it++){       // 1024 uint4: 32 rows x 32
    int q = tid + it*256;
    int row = q >> 5, c = q & 31;
    int g = gids[row];
    if(g >= 0)
      *(uint4*)(KVn + (size_t)g*512 + (cb>>2)*8 + c*8) = ((uint4*)(smem + row*XSP))[c];
  }
  __syncthreads();                 // KV stage dead; reuse smem as Q stage (bf16)
  #pragma unroll
  for(int nt=0; nt<2; nt++){
    int lc = w*32 + nt*16 + l16;
    float bqv = bq[t*DD + cb + lc];
    #pragma unroll
    for(int mt=0; mt<2; mt++){
      #pragma unroll
      for(int reg=0; reg<4; reg++){
        int row = mt*16 + quad*4 + reg;
        smem[row*XSP + lc] = f2bf(accQ[mt][nt][reg] + bqv);
      }
    }
  }
  __syncthreads();
  // ---- QA stage: wave w = head h; smem reused as per-r QA output staging ----
  int h = (cb >> 5) + w;
  bf16x8 qf0 = *(const bf16x8*)(smem + l16*XSP + w*32 + quad*8);
  bf16x8 qf1 = *(const bf16x8*)(smem + (16+l16)*XSP + w*32 + quad*8);
  for(int r=0; r<NR; r++){
    f32x4 acc[2][2];   // [mt][nt]
    #pragma unroll
    for(int mt=0;mt<2;mt++)
      #pragma unroll
      for(int nt=0;nt<2;nt++) acc[mt][nt]=(f32x4)(0.f);
    const u16* ap = Atb + (size_t)(r*NH + h)*1024;
    bf16x8 b0 = *(const bf16x8*)(ap + l16*32 + quad*8);
    bf16x8 b1 = *(const bf16x8*)(ap + (16+l16)*32 + quad*8);
    acc[0][0] = __builtin_amdgcn_mfma_f32_16x16x32_bf16(qf0, b0, acc[0][0], 0,0,0);
    acc[0][1] = __builtin_amdgcn_mfma_f32_16x16x32_bf16(qf0, b1, acc[0][1], 0,0,0);
    acc[1][0] = __builtin_amdgcn_mfma_f32_16x16x32_bf16(qf1, b0, acc[1][0], 0,0,0);
    acc[1][1] = __builtin_amdgcn_mfma_f32_16x16x32_bf16(qf1, b1, acc[1][1], 0,0,0);
    __syncthreads();               // prev r's output reads done (and r=0: Q frag loads done)
    #pragma unroll
    for(int mt=0; mt<2; mt++)
      #pragma unroll
      for(int nt=0; nt<2; nt++)
        #pragma unroll
        for(int reg=0; reg<4; reg++){
          int row = mt*16 + quad*4 + reg;
          smem[row*XSP + w*32 + nt*16 + l16] = f2bf(acc[mt][nt][reg]);
        }
    __syncthreads();
    #pragma unroll
    for(int it=0; it<2; it++){     // 512 uint4: 32 rows x 16 (128 u16/row)
      int q = tid + it*256;
      int row = q >> 4, c = q & 15;
      int g = gids[row];
      if(g >= 0)
        *(uint4*)(QA + ((size_t)g*NR + r)*DD + cb + c*8) = ((uint4*)(smem + row*XSP))[c];
    }
  }
}

// ---------------- fused per-node softmax + aggregation: r-sorted, batched gathers ----------
// (R12 structure — latency/fabric floor for random 1KB gathers.)
#define VSP 264
__global__ __launch_bounds__(256) void k_edge(
    const u16* __restrict__ KVn, const u16* __restrict__ QA,
    const int* __restrict__ off2, const int* __restrict__ packed,
    const int* __restrict__ pos2, u16* __restrict__ aggrV)
{
  int lane = threadIdx.x & 63;
  int n = blockIdx.x*4 + (threadIdx.x >> 6);
  if(n >= NN) return;
  int off = lane*4;                  // = h*32 + j*4 with h=lane>>3
  float4 qa[NR];
  {
    const u16* qp = QA + (size_t)n*NR*DD + off;
    #pragma unroll
    for(int r=0;r<NR;r++){
      ushort4 q = *(const ushort4*)(qp + r*DD);
      qa[r] = make_float4(bf2f(q.x),bf2f(q.y),bf2f(q.z),bf2f(q.w));
    }
  }
  int eb[NR+1];
  eb[0] = (n==0) ? 0 : off2[n*NR - 1];
  #pragma unroll
  for(int i=1;i<=NR;i++) eb[i] = off2[n*NR + i - 1];
  float4 acc[NR];
  float s = 0.f;
  int lo8 = lane*8;

  #define EDGE_DOT(kv, q, dd) \
    { float k0=__uint_as_float((kv).x<<16), k1=__uint_as_float((kv).x&0xffff0000u); \
      float k2=__uint_as_float((kv).y<<16), k3=__uint_as_float((kv).y&0xffff0000u); \
      dd = k0*(q).x + k1*(q).y + k2*(q).z + k3*(q).w; }
  #define EDGE_ACC(kv, p, a) \
    { float v0=__uint_as_float((kv).z<<16), v1=__uint_as_float((kv).z&0xffff0000u); \
      float v2=__uint_as_float((kv).w<<16), v3=__uint_as_float((kv).w&0xffff0000u); \
      (a).x += (p)*v0; (a).y += (p)*v1; (a).z += (p)*v2; (a).w += (p)*v3; }
  #define RED3(d) { d += __shfl_xor(d,1); d += __shfl_xor(d,2); d += __shfl_xor(d,4); }

  #pragma unroll
  for(int r=0;r<NR;r++){
    float4 q = qa[r];
    float4 a = make_float4(0.f,0.f,0.f,0.f);
    int e = eb[r], end = eb[r+1];
    for(; e+4 <= end; e += 4){
      int s0 = packed[e], s1 = packed[e+1], s2 = packed[e+2], s3 = packed[e+3];
      uint4 kv0 = *(const uint4*)(KVn + (size_t)s0*512 + lo8);
      uint4 kv1 = *(const uint4*)(KVn + (size_t)s1*512 + lo8);
      uint4 kv2 = *(const uint4*)(KVn + (size_t)s2*512 + lo8);
      uint4 kv3 = *(const uint4*)(KVn + (size_t)s3*512 + lo8);
      float d0,d1,d2,d3;
      EDGE_DOT(kv0,q,d0); EDGE_DOT(kv1,q,d1); EDGE_DOT(kv2,q,d2); EDGE_DOT(kv3,q,d3);
      RED3(d0); RED3(d1); RED3(d2); RED3(d3);
      float p0=__expf(d0), p1=__expf(d1), p2=__expf(d2), p3=__expf(d3);
      s += p0 + p1 + p2 + p3;
      EDGE_ACC(kv0,p0,a); EDGE_ACC(kv1,p1,a); EDGE_ACC(kv2,p2,a); EDGE_ACC(kv3,p3,a);
    }
    if(e+2 <= end){
      int s0 = packed[e], s1 = packed[e+1];
      uint4 kv0 = *(const uint4*)(KVn + (size_t)s0*512 + lo8);
      uint4 kv1 = *(const uint4*)(KVn + (size_t)s1*512 + lo8);
      float d0,d1;
      EDGE_DOT(kv0,q,d0); EDGE_DOT(kv1,q,d1);
      RED3(d0); RED3(d1);
      float p0=__expf(d0), p1=__expf(d1);
      s += p0 + p1;
      EDGE_ACC(kv0,p0,a); EDGE_ACC(kv1,p1,a);
      e += 2;
    }
    if(e < end){
      int s0 = packed[e];
      uint4 kv0 = *(const uint4*)(KVn + (size_t)s0*512 + lo8);
      float d0;
      EDGE_DOT(kv0,q,d0);
      RED3(d0);
      float p0=__expf(d0);
      s += p0;
      EDGE_ACC(kv0,p0,a);
    }
    acc[r] = a;
  }
  #undef EDGE_DOT
  #undef EDGE_ACC
  #undef RED3
  float inv = (s > 0.f) ? (1.f/s) : 0.f;
  int p = pos2[n];                   // perm-order row for contiguous k_mo reads
  u16* op = aggrV + (size_t)p*NR*DD + off;
  #pragma unroll
  for(int r=0;r<NR;r++){
    ushort4 o;
    o.x=f2bf(acc[r].x*inv); o.y=f2bf(acc[r].y*inv);
    o.z=f2bf(acc[r].z*inv); o.w=f2bf(acc[r].w*inv);
    *(ushort4*)(op + r*DD) = o;
  }
}

// ---------------- FUSED k_msg + k_out (aggrV perm-ordered; stage-1 double-buffered) ------
// Stage-1 staging alternates Vs <-> h2s (h2s is dead until stage 2): one barrier per
// relation instead of two. Load/read patterns byte-identical (R18 lesson: keep them).
__global__ __launch_bounds__(256) void k_mo(
    const u16* __restrict__ aggrV, const u16* __restrict__ Mtm,
    const float* __restrict__ x,
    const int* __restrict__ perm, const int* __restrict__ boff,
    const u16* __restrict__ Wta, const float* __restrict__ ba,
    const u16* __restrict__ Wot, const float* __restrict__ bo,
    float* __restrict__ out)
{
  __shared__ u16 Vs[32*VSP];
  __shared__ u16 hs[32*VSP];
  __shared__ u16 h2s[32*VSP];
  __shared__ int gids[32];
  int tid = threadIdx.x;
  int ts = blockIdx.x*32;
  int t = (ts >= boff[2]) ? 2 : (ts >= boff[1]) ? 1 : 0;
  if(tid < 32) gids[tid] = perm[ts + tid];
  __syncthreads();
  int lane = tid & 63, w = tid >> 6, quad = lane >> 4, l16 = lane & 15;

  // ---- stage 1: rel_msg MFMA over r, double-buffered (Vs / h2s) ----
  f32x4 macc[2][2][2];
  #pragma unroll
  for(int hh=0;hh<2;hh++)
    #pragma unroll
    for(int mt=0;mt<2;mt++)
      #pragma unroll
      for(int nt=0;nt<2;nt++) macc[hh][mt][nt]=(f32x4)(0.f);
  #pragma unroll
  for(int r=0;r<NR;r++){
    u16* B = (r & 1) ? h2s : Vs;
    #pragma unroll
    for(int it=0; it<4; it++){
      int q = tid + it*256;
      int row = q >> 5, c = q & 31;
      ((uint4*)(B + row*VSP))[c] =
        ((const uint4*)(aggrV + ((size_t)(ts+row)*NR + r)*DD))[c];
    }
    __syncthreads();   // single barrier: prior buffer's reads retired before next overwrite
    #pragma unroll
    for(int hh=0; hh<2; hh++){
      int h = w*2 + hh;
      bf16x8 a0 = *(const bf16x8*)(B + l16*VSP + h*32 + quad*8);
      bf16x8 a1 = *(const bf16x8*)(B + (16+l16)*VSP + h*32 + quad*8);
      const u16* mp = Mtm + ((size_t)(r*NH + h)*32)*32;
      bf16x8 b0 = *(const bf16x8*)(mp + l16*32 + quad*8);
      bf16x8 b1 = *(const bf16x8*)(mp + (16+l16)*32 + quad*8);
      macc[hh][0][0] = __builtin_amdgcn_mfma_f32_16x16x32_bf16(a0, b0, macc[hh][0][0], 0,0,0);
      macc[hh][0][1] = __builtin_amdgcn_mfma_f32_16x16x32_bf16(a0, b1, macc[hh][0][1], 0,0,0);
      macc[hh][1][0] = __builtin_amdgcn_mfma_f32_16x16x32_bf16(a1, b0, macc[hh][1][0], 0,0,0);
      macc[hh][1][1] = __builtin_amdgcn_mfma_f32_16x16x32_bf16(a1, b1, macc[hh][1][1], 0,0,0);
    }
  }
  // ELU -> hs (bf16, in LDS)
  #pragma unroll
  for(int hh=0; hh<2; hh++){
    int h = w*2 + hh;
    #pragma unroll
    for(int mt=0; mt<2; mt++){
      #pragma unroll
      for(int nt=0; nt<2; nt++){
        #pragma unroll
        for(int reg=0; reg<4; reg++){
          int row = mt*16 + quad*4 + reg;
          float v = macc[hh][mt][nt][reg];
          v = (v > 0.f) ? v : expm1f(v);
          hs[row*VSP + h*32 + nt*16 + l16] = f2bf(v);
        }
      }
    }
  }
  __syncthreads();

  // ---- stage 2: Wa MFMA + residual + classifier + log_softmax ----
  f32x4 acc[2][4];
  #pragma unroll
  for(int mt=0;mt<2;mt++)
    #pragma unroll
    for(int nt=0;nt<4;nt++) acc[mt][nt]=(f32x4)(0.f);
  const u16* wap = Wta + (size_t)t*65536;
  #pragma unroll
  for(int kk=0; kk<8; kk++){
    int kb = kk*32 + quad*8;
    bf16x8 a0 = *(const bf16x8*)(hs + l16*VSP + kb);
    bf16x8 a1 = *(const bf16x8*)(hs + (16+l16)*VSP + kb);
    #pragma unroll
    for(int nt=0; nt<4; nt++){
      int n = w*64 + nt*16 + l16;
      bf16x8 b = *(const bf16x8*)(wap + (size_t)n*DD + kb);
      acc[0][nt] = __builtin_amdgcn_mfma_f32_16x16x32_bf16(a0, b, acc[0][nt], 0,0,0);
      acc[1][nt] = __builtin_amdgcn_mfma_f32_16x16x32_bf16(a1, b, acc[1][nt], 0,0,0);
    }
  }
  #pragma unroll
  for(int nt=0; nt<4; nt++){
    int colg = w*64 + nt*16 + l16;
    float bav = ba[t*DD + colg];
    #pragma unroll
    for(int mt=0; mt<2; mt++){
      #pragma unroll
      for(int reg=0; reg<4; reg++){
        int row = mt*16 + quad*4 + reg;
        int g = gids[row];
        float xr = (g>=0) ? x[(size_t)g*DD + colg] : 0.f;
        h2s[row*VSP + colg] = f2bf(acc[mt][nt][reg] + bav + xr);
      }
    }
  }
  __syncthreads();
  if(w < 2){
    f32x4 cacc = (f32x4)(0.f);
    #pragma unroll
    for(int kk=0; kk<8; kk++){
      int kb = kk*32 + quad*8;
      bf16x8 a = *(const bf16x8*)(h2s + (w*16 + l16)*VSP + kb);
      bf16x8 b = *(const bf16x8*)(Wot + (size_t)l16*DD + kb);
      cacc = __builtin_amdgcn_mfma_f32_16x16x32_bf16(a, b, cacc, 0,0,0);
    }
    float bov = bo[l16];
    #pragma unroll
    for(int reg=0; reg<4; reg++){
      int row = w*16 + quad*4 + reg;
      int g = gids[row];
      float v = cacc[reg] + bov;     // col = l16 = class
      float m = v;
      m = fmaxf(m, __shfl_xor(m,1)); m = fmaxf(m, __shfl_xor(m,2));
      m = fmaxf(m, __shfl_xor(m,4)); m = fmaxf(m, __shfl_xor(m,8));
      float p = __expf(v - m);
      p += __shfl_xor(p,1); p += __shfl_xor(p,2);
      p += __shfl_xor(p,4); p += __shfl_xor(p,8);
      float lse = m + __logf(p);
      if(g >= 0) out[(size_t)g*NC + l16] = v - lse;
    }
  }
}

extern "C" void kernel_launch(void* const* d_in, const int* in_sizes, int n_in,
                              void* d_out, int out_size, void* d_ws, size_t ws_size,
                              hipStream_t stream)
{
  const float* x     = (const float*)d_in[0];
  const int*   ei    = (const int*)d_in[1];
  const int*   ntype = (const int*)d_in[2];
  const int*   etype = (const int*)d_in[3];
  const float* Wk    = (const float*)d_in[4];
  const float* bk    = (const float*)d_in[5];
  const float* Wq    = (const float*)d_in[6];
  const float* bq    = (const float*)d_in[7];
  const float* Wv    = (const float*)d_in[8];
  const float* bv    = (const float*)d_in[9];
  const float* Wa    = (const float*)d_in[10];
  const float* ba    = (const float*)d_in[11];
  const float* prior = (const float*)d_in[12];
  const float* ratt  = (const float*)d_in[13];
  const float* rmsg  = (const float*)d_in[14];
  const float* Wo    = (const float*)d_in[15];
  const float* bo    = (const float*)d_in[16];
  float* out = (float*)d_out;

  char* ws = (char*)d_ws;
  int* iw      = (int*)ws;
  int* cnt     = iw + 0;
  int* bcur    = iw + 4;
  int* boff    = iw + 8;
  int* off2    = iw + 16;                 // NN*NR+1 = 100001 ints
  int* perm    = iw + 100032;             // 20096 ints
  int* packed  = iw + 120128;             // NE ints (ends 440128)
  int* bsum    = iw + 440128;             // 512 ints (ends 440640)
  int* pos2    = iw + 440640;             // NN ints (ends 460640)

  size_t fb = 1842688;                    // 460640*4 = 1842560, 256-aligned up
  u16*   KVn   = (u16*)(ws + fb);   fb += 2ull*NN*512;         // 20.48 MB (K,V interleaved)
  u16*   QA    = (u16*)(ws + fb);   fb += 2ull*NN*NR*DD;       // 51.2 MB
  u16*   aggrV = (u16*)(ws + fb);   fb += 2ull*20096*NR*DD;    // 51.45 MB (perm-order, padded)
  u16*   Wtk   = (u16*)(ws + fb);   fb += 2ull*3*65536;
  u16*   Wtq   = (u16*)(ws + fb);   fb += 2ull*3*65536;
  u16*   Wtv   = (u16*)(ws + fb);   fb += 2ull*3*65536;
  u16*   Wta   = (u16*)(ws + fb);   fb += 2ull*3*65536;
  u16*   Wot   = (u16*)(ws + fb);   fb += 2ull*NC*DD;
  u16*   Mtm   = (u16*)(ws + fb);   fb += 2ull*NR*NH*KK*KK;
  u16*   Atb   = (u16*)(ws + fb);   fb += 2ull*NR*NH*KK*KK;
  // total ~127 MB (validated high-water mark: 165.6 MB)
  u16* xb = aggrV;                        // NN*DD bf16 alias; dead before k_edge writes

  hipMemsetAsync(iw, 0, (size_t)(16 + NN*NR + 1)*sizeof(int), stream); // cnt,bcur,boff,off2

  k_pre1   <<<1408, 256, 0, stream>>>(ntype, ei, etype, cnt, off2, perm);
  k_pre2   <<<NB2+1, 256, 0, stream>>>(off2, bsum, cnt, boff);
  k_scan2  <<<1, 512, 0, stream>>>(bsum, off2);
  k_pre3   <<<NB2+79, 256, 0, stream>>>(off2, bsum, ntype, boff, bcur, perm, pos2);
  k_work1  <<<4854, 256, 0, stream>>>(ei, etype, off2, packed, x, xb,
                                      Wk, Wq, Wv, Wa, Wtk, Wtq, Wtv, Wta,
                                      rmsg, ratt, prior, Wo, Mtm, Atb, Wot);
  k_projqa <<<1256, 256, 0, stream>>>(xb, perm, boff, Wtk, Wtq, Wtv, bk, bq, bv,
                                      Atb, KVn, QA);
  k_edge   <<<5000, 256, 0, stream>>>(KVn, QA, off2, packed, pos2, aggrV);
  k_mo     <<<628, 256, 0, stream>>>(aggrV, Mtm, x, perm, boff, Wta, ba, Wot, bo, out);
}